// Round 9
// baseline (2573.227 us; speedup 1.0000x reference)
//
#include <hip/hip_runtime.h>
#include <hip/hip_bf16.h>
#include <cstddef>
#include <cstdint>

#define T_SEQ 512
#define BATCH 256
#define RTOT (BATCH * T_SEQ) /* 131072 rows */

__device__ __forceinline__ float fsigmoid(float x) {
    return 1.0f / (1.0f + __expf(-x));
}
__device__ __forceinline__ float ftanh(float x) {
    // tanh(x) = 1 - 2/(exp(2x)+1); saturates correctly at +-inf
    return 1.0f - 2.0f / (__expf(2.0f * x) + 1.0f);
}

// ---------------------------------------------------------------------------
// Input projection: xp[r, 0:192] = x[r, :] @ W + bi   for both directions.
// (unchanged for attribution)
// ---------------------------------------------------------------------------
template <int DIN, bool EMBED>
__global__ __launch_bounds__(192) void proj_kernel(
    const float* __restrict__ X, const int* __restrict__ tokens,
    const float* __restrict__ emb,
    const float* __restrict__ Wf, const float* __restrict__ bf_,
    const float* __restrict__ Wb, const float* __restrict__ bb_,
    float* __restrict__ xpf, float* __restrict__ xpb)
{
    constexpr int ROWS = 32;
    constexpr int PAD = 36; // row stride 144B: 16B-aligned float4 reads
    __shared__ __align__(16) float xt[DIN][PAD];
    const int r0 = blockIdx.x * ROWS;
    const int tid = threadIdx.x;

    for (int e = tid; e < ROWS * DIN; e += 192) {
        const int row = e / DIN;
        const int i = e % DIN;
        float v;
        if (EMBED) {
            v = emb[(size_t)tokens[r0 + row] * 64 + i];
        } else {
            v = X[(size_t)(r0 + row) * DIN + i];
        }
        xt[i][row] = v;
    }
    __syncthreads();

    const int col = tid; // 0..191
    #pragma unroll
    for (int d = 0; d < 2; d++) {
        const float* __restrict__ W = d ? Wb : Wf;
        const float* __restrict__ bi = d ? bb_ : bf_;
        float* __restrict__ outp = d ? xpb : xpf;
        float acc[ROWS];
        const float b0 = bi[col];
        #pragma unroll
        for (int r = 0; r < ROWS; r++) acc[r] = b0;
        #pragma unroll 4
        for (int i = 0; i < DIN; i++) {
            const float w = W[i * 192 + col]; // coalesced, L1/L2-hot
            #pragma unroll
            for (int r = 0; r < ROWS; r += 4) {
                const float4 x4 = *(const float4*)&xt[i][r];
                acc[r + 0] = fmaf(x4.x, w, acc[r + 0]);
                acc[r + 1] = fmaf(x4.y, w, acc[r + 1]);
                acc[r + 2] = fmaf(x4.z, w, acc[r + 2]);
                acc[r + 3] = fmaf(x4.w, w, acc[r + 3]);
            }
        }
        #pragma unroll
        for (int r = 0; r < ROWS; r++) {
            outp[(size_t)(r0 + r) * 192 + col] = acc[r];
        }
    }
}

// ---------------------------------------------------------------------------
// Recurrent scan v9: 3 waves (192 threads) per (batch,direction) chain;
// thread k owns gate column k. Unified-theory fixes (r0-r8 post-mortem):
//
//  1. Weights AGPR-parked ("=a" asm; r5/r8 proved residency -- the VGPR
//     allocator NEVER keeps a 64-deep array live otherwise).
//  2. Per-step sync has NO "memory" clobber anywhere: an asm with
//     ::: "memory" forces the waitcnt pass to drain vmcnt(0) (it must assume
//     the asm touches any memory) -- that was the hidden per-step HBM-latency
//     stall in r0 (__syncthreads), r6/r7/r8 ("lgkm-only" barriers with
//     memory clobbers). Here: sched_barrier(0) pins the volatile ds_writes,
//     bare "s_waitcnt lgkmcnt(0)" orders LDS, raw s_barrier syncs,
//     sched_barrier(0) pins the reads below. vmcnt stays COUNTED: y-stores
//     and xp prefetches remain in flight across the barrier (T4 pattern,
//     m201-proven).
//  3. zrs exchange is volatile __shared__: compiler ordering vs the volatile
//     asm chain without a memory clobber.
//  4. xp prefetch via a VOLATILE pointer: the allocator otherwise SINKS
//     prefetch loads to their use when minimizing pressure (r2/r3/r5's
//     "depth-2" was depth-0 -> full latency per step). Volatile loads cannot
//     cross the sync block's volatile asm -> issued >=1 step before use.
//  5. h is per-wave-private (hw[g], parity double-buffered, plain LDS:
//     same-wave in-order ds ops; may-alias [j] store blocks bad hoists).
//     All waves redundantly compute hnew from zrs -> ONE barrier per step.
//     zrs 2-buffer + 1 barrier/step safety: writes of parity p at t+2 start
//     after barrier(t+1), which all waves reach only after their step-t
//     reads of parity p (validated in r8).
// Gate order matches jnp.split: [0:64]=z, [64:128]=r, [128:192]=h.
// Masked steps (tok==0) carry state; wave g==2 writes y/hfinal.
// Grid 512 = 2 blocks/CU: independent blocks interleave on shared SIMDs,
// hiding each other's exchange latency (TLP).
// ---------------------------------------------------------------------------
__global__ __launch_bounds__(192) void gru_scan(
    const float* __restrict__ xpf, const float* __restrict__ xpb,
    const float* __restrict__ whf, const float* __restrict__ whb,
    const float* __restrict__ bbf, const float* __restrict__ bbb,
    const int* __restrict__ tokens,
    float* __restrict__ y,        // [RTOT,128] or nullptr
    float* __restrict__ hfinal)   // [BATCH,128] or nullptr
{
    const int chain = blockIdx.x; // 0..511
    const int b = chain >> 1;
    const int dir = chain & 1;
    const float* __restrict__ xp = dir ? xpb : xpf;
    const volatile float* xpv = xp;      // volatile alias: prefetch can't sink
    const float* __restrict__ wh = dir ? whb : whf;
    const float* __restrict__ bbp_ = dir ? bbb : bbf;
    const int k = threadIdx.x;  // 0..191 = gate column
    const int j = k & 63;
    const int g = k >> 6;       // wave: 0=z, 1=r, 2=candidate

    __shared__ volatile float zrs[2][4][64];      // {z, r, rec_h, x_h} x parity
    __shared__ __align__(16) float hw[3][2][64];  // per-wave h double-buffer
    __shared__ int tokl[T_SEQ];

    // Park Wh[:,k] in AGPRs (64 values/thread, zero competing AGPR pressure).
    float wag[64];
    #pragma unroll
    for (int i = 0; i < 64; i++) {
        const float v = wh[i * 192 + k]; // coalesced per i
        asm volatile("v_accvgpr_write_b32 %0, %1" : "=a"(wag[i]) : "v"(v));
    }
    const float bhk = bbp_[192 + k]; // recurrent bias (bb row 1)

    const size_t base = (size_t)b * T_SEQ;
    for (int i = k; i < T_SEQ; i += 192) tokl[i] = tokens[base + i];
    hw[g][0][j] = 0.0f; // own-wave h init, parity 0

    const int t0 = dir ? (T_SEQ - 1) : 0;
    const int st = dir ? -1 : 1;

    // prefetch depth 2 (volatile -> actually issued here, not at use)
    float xv0 = xpv[(base + t0) * 192 + k];
    float xv1 = xpv[(base + t0 + st) * 192 + k];

    float hprev = 0.0f;
    float* yp = y ? (y + (base + t0) * 128 + (dir << 6) + j) : nullptr;
    const ptrdiff_t ystep = (ptrdiff_t)st * 128;
    int te = t0;

    __syncthreads(); // one-time full drain: tokens + h init visible

    for (int t = 0; t < T_SEQ; t++) {
        const int p = t & 1;
        // prefetch t+2 (volatile: pinned before the next sync block)
        const int tn = (t + 2 < T_SEQ) ? (t + 2) : (T_SEQ - 1);
        const float xv2 = xpv[(base + (size_t)(t0 + st * tn)) * 192 + k];

        // rec[k] = h . Wh[:,k] + bh[k]; h broadcast from OWN wave's LDS copy,
        // weights pulled from AGPR just-in-time; 4 accumulators.
        float a0 = bhk, a1 = 0.0f, a2 = 0.0f, a3 = 0.0f;
        #pragma unroll
        for (int i = 0; i < 64; i += 4) {
            const float4 h4 = *(const float4*)&hw[g][p][i];
            float w0, w1, w2, w3;
            asm volatile("v_accvgpr_read_b32 %0, %1" : "=v"(w0) : "a"(wag[i + 0]));
            asm volatile("v_accvgpr_read_b32 %0, %1" : "=v"(w1) : "a"(wag[i + 1]));
            asm volatile("v_accvgpr_read_b32 %0, %1" : "=v"(w2) : "a"(wag[i + 2]));
            asm volatile("v_accvgpr_read_b32 %0, %1" : "=v"(w3) : "a"(wag[i + 3]));
            a0 = fmaf(h4.x, w0, a0);
            a1 = fmaf(h4.y, w1, a1);
            a2 = fmaf(h4.z, w2, a2);
            a3 = fmaf(h4.w, w3, a3);
        }
        const float acc = (a0 + a1) + (a2 + a3);

        if (g == 0) {
            zrs[p][0][j] = fsigmoid(xv0 + acc);
        } else if (g == 1) {
            zrs[p][1][j] = fsigmoid(xv0 + acc);
        } else {
            zrs[p][2][j] = acc; // rec_h (bias included)
            zrs[p][3][j] = xv0; // x_h
        }

        // ---- sync block: LDS-ordered only; vmcnt stays counted ----
        __builtin_amdgcn_sched_barrier(0);
        asm volatile("s_waitcnt lgkmcnt(0)");
        __builtin_amdgcn_s_barrier();
        __builtin_amdgcn_sched_barrier(0);

        const float zg = zrs[p][0][j];
        const float rg = zrs[p][1][j];
        const float rh = zrs[p][2][j];
        const float xh = zrs[p][3][j];
        const float cand = ftanh(xh + rg * rh);
        float hnew = zg * hprev + (1.0f - zg) * cand;
        if (!(tokl[te] > 0)) hnew = hprev; // Keras mask: carry state
        hw[g][p ^ 1][j] = hnew;            // own-wave copy (in-order ds ops)
        if (g == 2 && yp) *yp = hnew;      // fire-and-forget (never drained)
        hprev = hnew;
        te += st;
        if (yp) yp += ystep;
        xv0 = xv1; xv1 = xv2;
    }
    if (hfinal && g == 2) {
        hfinal[b * 128 + (dir << 6) + j] = hprev;
    }
}

// ---------------------------------------------------------------------------
// MLP head: one block (1 wave) per batch row. (unchanged)
// ---------------------------------------------------------------------------
__global__ __launch_bounds__(64) void mlp_kernel(
    const float* __restrict__ hcat, // [BATCH,128]
    const float* __restrict__ wd1, const float* __restrict__ bd1,
    const float* __restrict__ wd2, const float* __restrict__ bd2,
    const float* __restrict__ wd3, const float* __restrict__ bd3,
    const float* __restrict__ wo, const float* __restrict__ bo,
    float* __restrict__ outp)       // [BATCH,28]
{
    const int b = blockIdx.x;
    const int j = threadIdx.x; // 0..63
    __shared__ float x0[128];
    __shared__ float x1[64];
    x0[j] = hcat[b * 128 + j];
    x0[j + 64] = hcat[b * 128 + 64 + j];
    __syncthreads();
    float a = bd1[j];
    #pragma unroll 4
    for (int i = 0; i < 128; i++) a = fmaf(x0[i], wd1[i * 64 + j], a);
    a = fmaxf(a, 0.0f);
    x1[j] = a;
    __syncthreads();
    float a2 = bd2[j];
    #pragma unroll 4
    for (int i = 0; i < 64; i++) a2 = fmaf(x1[i], wd2[i * 64 + j], a2);
    a2 = fmaxf(a2, 0.0f);
    __syncthreads();
    x1[j] = a2;
    __syncthreads();
    float a3 = bd3[j];
    #pragma unroll 4
    for (int i = 0; i < 64; i++) a3 = fmaf(x1[i], wd3[i * 64 + j], a3);
    a3 = fmaxf(a3, 0.0f);
    __syncthreads();
    x1[j] = a3;
    __syncthreads();
    if (j < 28) {
        float o = bo[j];
        #pragma unroll 4
        for (int i = 0; i < 64; i++) o = fmaf(x1[i], wo[i * 28 + j], o);
        outp[b * 28 + j] = fsigmoid(o);
    }
}

// ---------------------------------------------------------------------------
extern "C" void kernel_launch(void* const* d_in, const int* in_sizes, int n_in,
                              void* d_out, int out_size, void* d_ws, size_t ws_size,
                              hipStream_t stream)
{
    const int* tokens  = (const int*)d_in[0];
    const float* emb   = (const float*)d_in[1];
    const float* wi1f  = (const float*)d_in[2];
    const float* wh1f  = (const float*)d_in[3];
    const float* bb1f  = (const float*)d_in[4];
    const float* wi1b  = (const float*)d_in[5];
    const float* wh1b  = (const float*)d_in[6];
    const float* bb1b  = (const float*)d_in[7];
    const float* wi2f  = (const float*)d_in[8];
    const float* wh2f  = (const float*)d_in[9];
    const float* bb2f  = (const float*)d_in[10];
    const float* wi2b  = (const float*)d_in[11];
    const float* wh2b  = (const float*)d_in[12];
    const float* bb2b  = (const float*)d_in[13];
    const float* wi3f  = (const float*)d_in[14];
    const float* wh3f  = (const float*)d_in[15];
    const float* bb3f  = (const float*)d_in[16];
    const float* wi3b  = (const float*)d_in[17];
    const float* wh3b  = (const float*)d_in[18];
    const float* bb3b  = (const float*)d_in[19];
    const float* wd1   = (const float*)d_in[20];
    const float* bd1   = (const float*)d_in[21];
    const float* wd2   = (const float*)d_in[22];
    const float* bd2   = (const float*)d_in[23];
    const float* wd3   = (const float*)d_in[24];
    const float* bd3   = (const float*)d_in[25];
    const float* wo    = (const float*)d_in[26];
    const float* bo    = (const float*)d_in[27];

    // Workspace layout (all fp32) — total EXACTLY 256 MiB:
    //   y    : RTOT*128  (layer output, reused)        67,108,864 B
    //   xpf  : RTOT*192  (fwd input projection)       100,663,296 B
    //   xpb  : RTOT*192  (bwd input projection)       100,663,296 B
    //   hcat : BATCH*128 — ALIASED onto y's space (y is dead after proj3
    //          reads it; the layer-3 scan writes only hfinal).
    float* y    = (float*)d_ws;
    float* xpf  = y + (size_t)RTOT * 128;
    float* xpb  = xpf + (size_t)RTOT * 192;
    float* hcat = y; // alias: y region is dead by the time hcat is written

    const dim3 pb(192), pg(RTOT / 32);

    // Layer 1 (embedding fused into projection)
    proj_kernel<64, true><<<pg, pb, 0, stream>>>(nullptr, tokens, emb,
                                                 wi1f, bb1f, wi1b, bb1b, xpf, xpb);
    gru_scan<<<512, 192, 0, stream>>>(xpf, xpb, wh1f, wh1b, bb1f, bb1b,
                                      tokens, y, nullptr);
    // Layer 2
    proj_kernel<128, false><<<pg, pb, 0, stream>>>(y, nullptr, nullptr,
                                                   wi2f, bb2f, wi2b, bb2b, xpf, xpb);
    gru_scan<<<512, 192, 0, stream>>>(xpf, xpb, wh2f, wh2b, bb2f, bb2b,
                                      tokens, y, nullptr);
    // Layer 3 (final states only)
    proj_kernel<128, false><<<pg, pb, 0, stream>>>(y, nullptr, nullptr,
                                                   wi3f, bb3f, wi3b, bb3b, xpf, xpb);
    gru_scan<<<512, 192, 0, stream>>>(xpf, xpb, wh3f, wh3b, bb3f, bb3b,
                                      tokens, nullptr, hcat);
    // Head
    mlp_kernel<<<256, 64, 0, stream>>>(hcat, wd1, bd1, wd2, bd2, wd3, bd3,
                                       wo, bo, (float*)d_out);
}